// Round 13
// baseline (569.708 us; speedup 1.0000x reference)
//
#include <hip/hip_runtime.h>

// ---------------- problem constants ----------------
#define NVEC  131072      // 32*4096 vectors
#define DIM   64
#define K     512
#define DECAYF 0.99f
#define OMDF   0.01f
#define EPSF   1e-5f
#define VPB   128                 // vectors per block: 64 lanes x 2 vectors
#define NBLK_ASSIGN (NVEC / VPB)  // 1024 blocks, 4 waves each
#define NBLK_STATS  32            // stats blocks (4096 vectors each)

// ---------------- output layout (floats, concatenated in return order) ----
#define Q_OFF    0
#define DIFF_OFF 8388608
#define IND_OFF  8388609
#define NE_OFF   8519681
#define NCS_OFF  8552449
#define NEA_OFF  8552961

// ---------------- ws layout (floats) ----
#define ET_OFF    0        // E^T : K x DIM
#define C_OFF     32768    // np-order sum(E*E, axis=0) : K
#define DPART_OFF 33280    // per-assign-block diff partials : 1024
#define INDI_OFF  35328    // int copy of indices : NVEC
#define PCNT_OFF  166400   // atomic count accum : K          (zeroed by prep)
#define PESUM_OFF 166912   // atomic esum accum  : K x DIM    (zeroed by prep)
#define STATZ_N   (K + K * DIM)   // 33280 floats to zero
// end: 199680 floats (well under the known-safe 1.33 MB)

// ============ prep: transpose embed -> E^T, C_j; zero atomic stats =======
__global__ __launch_bounds__(256) void vq_prep(const float* __restrict__ embed,
                                               float* __restrict__ ws) {
    #pragma clang fp contract(off)
    int bid = blockIdx.x;
    if (bid < 2) {
        int j = bid * 256 + threadIdx.x;
        float c = 0.0f;
        for (int d = 0; d < DIM; ++d) {
            float v = embed[d * K + j];           // coalesced across j
            ws[ET_OFF + j * DIM + d] = v;
            float t = v * v;
            c = c + t;
        }
        ws[C_OFF + j] = c;
    } else {
        int i = (bid - 2) * 256 + threadIdx.x;    // 0..33279
        ws[PCNT_OFF + i] = 0.0f;                  // pcnt then pesum (contiguous)
    }
}

// ============ main: np-fp32-replica argmin — R9-exact (best: 163 µs) =====
// Converged after 10 rounds of pipe exploration: SMEM e-stream + R=2
// dual-chain + wpe(3). VMEM e-path dead (R2 592 / R10 973 µs); LDS
// broadcast dead (R3 254 µs); SMEM+R=1 inflates VALU 2.4x (R1); fused
// atomic stats dead (R12: 8.4M same-address atomics, 256 adds/address ->
// L2 serialization, +104 µs).
__global__ __launch_bounds__(256)
__attribute__((amdgpu_waves_per_eu(3)))
void vq_assign(
    const float* __restrict__ x,
    const float* __restrict__ ET,      // ws + ET_OFF
    const float* __restrict__ C,       // ws + C_OFF
    int*   __restrict__ indI,          // ws + INDI_OFF
    float* __restrict__ dpart,         // ws + DPART_OFF
    float* __restrict__ out)
{
    #pragma clang fp contract(off)
    __shared__ float sda[4][64], sdb[4][64];
    __shared__ int   sia[4][64], sib[4][64];
    __shared__ int   sba[64], sbb[64];
    __shared__ float wdl[4];

    int lane = threadIdx.x & 63;
    int wq   = __builtin_amdgcn_readfirstlane(threadIdx.x >> 6); // 0..3
    int va   = blockIdx.x * VPB + lane;
    int vb   = va + 64;
    const float* fxa = x + (size_t)va * DIM;
    const float* fxb = x + (size_t)vb * DIM;

    float fa[DIM], fb[DIM];
    #pragma unroll
    for (int k = 0; k < DIM / 4; ++k) {
        float4 t = ((const float4*)fxa)[k];
        fa[4*k+0] = t.x; fa[4*k+1] = t.y; fa[4*k+2] = t.z; fa[4*k+3] = t.w;
    }
    #pragma unroll
    for (int k = 0; k < DIM / 4; ++k) {
        float4 t = ((const float4*)fxb)[k];
        fb[4*k+0] = t.x; fb[4*k+1] = t.y; fb[4*k+2] = t.z; fb[4*k+3] = t.w;
    }

    // Pin fa/fb in VGPRs (identity asm: values defined by asm can't be
    // rematerialized from memory).
    #define PIN16(a, b) asm volatile("" \
        : "+v"(a[(b)+0]),  "+v"(a[(b)+1]),  "+v"(a[(b)+2]),  "+v"(a[(b)+3]), \
          "+v"(a[(b)+4]),  "+v"(a[(b)+5]),  "+v"(a[(b)+6]),  "+v"(a[(b)+7]), \
          "+v"(a[(b)+8]),  "+v"(a[(b)+9]),  "+v"(a[(b)+10]), "+v"(a[(b)+11]), \
          "+v"(a[(b)+12]), "+v"(a[(b)+13]), "+v"(a[(b)+14]), "+v"(a[(b)+15]))
    PIN16(fa, 0); PIN16(fa, 16); PIN16(fa, 32); PIN16(fa, 48);
    PIN16(fb, 0); PIN16(fb, 16); PIN16(fb, 32); PIN16(fb, 48);
    #undef PIN16

    // A per vector: numpy pairwise, n=64 -> 8 accumulators stride 8, then
    // ((r0+r1)+(r2+r3))+((r4+r5)+(r6+r7)). Plain mul+add (contract off).
    float ra[8], rb[8];
    #pragma unroll
    for (int k = 0; k < 8; ++k) { ra[k] = fa[k] * fa[k]; rb[k] = fb[k] * fb[k]; }
    #pragma unroll
    for (int b = 1; b < 8; ++b) {
        #pragma unroll
        for (int k = 0; k < 8; ++k) {
            float t0 = fa[8*b + k] * fa[8*b + k];
            ra[k] = ra[k] + t0;
            float t1 = fb[8*b + k] * fb[8*b + k];
            rb[k] = rb[k] + t1;
        }
    }
    float Aa = ((ra[0] + ra[1]) + (ra[2] + ra[3])) + ((ra[4] + ra[5]) + (ra[6] + ra[7]));
    float Ab = ((rb[0] + rb[1]) + (rb[2] + rb[3])) + ((rb[4] + rb[5]) + (rb[6] + rb[7]));

    // wave-uniform code segment -> s_load e-stream; one scalar feeds 2 FMAs.
    const float* eseg = ET + (size_t)wq * 128 * DIM;
    const float* Cseg = C + wq * 128;
    float bda = 3.0e38f, bdb = 3.0e38f;
    int   bia = wq * 128, bib = wq * 128;
    #pragma unroll 1
    for (int jj = 0; jj < 128; ++jj) {
        const float* e = eseg + jj * DIM;
        float ma = 0.0f, mb = 0.0f;
        #pragma unroll
        for (int d = 0; d < DIM; ++d) {
            float ev = e[d];
            ma = __builtin_fmaf(fa[d], ev, ma);
            mb = __builtin_fmaf(fb[d], ev, mb);
        }
        int j = wq * 128 + jj;
        float Cv = Cseg[jj];
        float t1a = 2.0f * ma;           // exact (x2)
        float t2a = Aa - t1a;            // rounded
        float da  = t2a + Cv;            // rounded
        float t1b = 2.0f * mb;
        float t2b = Ab - t1b;
        float db  = t2b + Cv;
        if (da < bda) { bda = da; bia = j; }
        if (db < bdb) { bdb = db; bib = j; }
    }

    sda[wq][lane] = bda; sia[wq][lane] = bia;
    sdb[wq][lane] = bdb; sib[wq][lane] = bib;
    __syncthreads();

    if (wq == 0) {
        // 4-way merge, ascending q, tie -> smaller index: numpy first-min.
        float bd = sda[0][lane]; int bi = sia[0][lane];
        #pragma unroll
        for (int q = 1; q < 4; ++q) {
            float d2 = sda[q][lane]; int i2 = sia[q][lane];
            if (d2 < bd || (d2 == bd && i2 < bi)) { bd = d2; bi = i2; }
        }
        sba[lane] = bi;
        out[IND_OFF + va] = (float)bi;   // coalesced
        indI[va] = bi;

        bd = sdb[0][lane]; bi = sib[0][lane];
        #pragma unroll
        for (int q = 1; q < 4; ++q) {
            float d2 = sdb[q][lane]; int i2 = sib[q][lane];
            if (d2 < bd || (d2 == bd && i2 < bi)) { bd = d2; bi = i2; }
        }
        sbb[lane] = bi;
        out[IND_OFF + vb] = (float)bi;
        indI[vb] = bi;
    }
    __syncthreads();

    // epilogue: wave0 -> va rows (vs pinned fa), wave1 -> vb rows (vs fb);
    // waves 2,3 idle (wdl = 0, dpart grouping stays wdl[0]+wdl[1]).
    float dl = 0.0f;
    if (wq == 0) {
        int bsel = sba[lane];
        const float4* qr = (const float4*)(ET + (size_t)bsel * DIM);
        float4* orow = (float4*)(out + Q_OFF + (size_t)va * DIM);
        #pragma unroll
        for (int k = 0; k < 16; ++k) {
            float4 tq = qr[k];
            float r0 = tq.x - fa[4*k+0];
            float r1 = tq.y - fa[4*k+1];
            float r2 = tq.z - fa[4*k+2];
            float r3 = tq.w - fa[4*k+3];
            dl = __builtin_fmaf(r0, r0, dl); dl = __builtin_fmaf(r1, r1, dl);
            dl = __builtin_fmaf(r2, r2, dl); dl = __builtin_fmaf(r3, r3, dl);
            orow[k] = tq;
        }
    } else if (wq == 1) {
        int bsel = sbb[lane];
        const float4* qr = (const float4*)(ET + (size_t)bsel * DIM);
        float4* orow = (float4*)(out + Q_OFF + (size_t)vb * DIM);
        #pragma unroll
        for (int k = 0; k < 16; ++k) {
            float4 tq = qr[k];
            float r0 = tq.x - fb[4*k+0];
            float r1 = tq.y - fb[4*k+1];
            float r2 = tq.z - fb[4*k+2];
            float r3 = tq.w - fb[4*k+3];
            dl = __builtin_fmaf(r0, r0, dl); dl = __builtin_fmaf(r1, r1, dl);
            dl = __builtin_fmaf(r2, r2, dl); dl = __builtin_fmaf(r3, r3, dl);
            orow[k] = tq;
        }
    }

    #pragma unroll
    for (int off = 32; off > 0; off >>= 1) dl += __shfl_down(dl, off);
    if (lane == 0) wdl[wq] = dl;
    __syncthreads();
    if (threadIdx.x == 0)
        dpart[blockIdx.x] = ((wdl[0] + wdl[1]) + (wdl[2] + wdl[3]));
}

// ============ stats: LDS-accumulation scatter (replaces ballot-gather) ===
// 32 blocks x 512 threads; each block owns a private acc[K][DIM] in LDS
// (exactly 128 KiB — HW-verified feasible) and walks its 4096 vectors:
// one coalesced x-row load + one ds_add_f32 per vector (bi wave-uniform;
// 64 lanes hit 64 consecutive words = 2-way bank aliasing = free). Flush:
// <=1M global atomics where each address receives <=32 adds (vs R12's 256
// -> no L2 same-address serialization). Counts: 1 global atomic per
// vector -> exact integers -> ncs/n bit-identical. pesum ordering is
// nondeterministic (same class as R12, which passed at absmax 0.0078).
__global__ __launch_bounds__(512) void vq_stats(
    const float* __restrict__ x,
    const int* __restrict__ indI,      // ws + INDI_OFF
    float* __restrict__ pcnt,          // ws + PCNT_OFF  (atomic)
    float* __restrict__ pesum)         // ws + PESUM_OFF (atomic)
{
    __shared__ float acc[K][DIM];      // 128 KiB
    int tid  = threadIdx.x;
    int lane = tid & 63;
    int w    = __builtin_amdgcn_readfirstlane(tid >> 6);   // 0..7

    // zero LDS: 64 stores per thread
    #pragma unroll 8
    for (int i = tid; i < K * DIM; i += 512) ((float*)acc)[i] = 0.0f;
    __syncthreads();

    // each wave walks a contiguous 512-vector chunk (coalesced x rows)
    int base = blockIdx.x * (NVEC / NBLK_STATS) + w * (NVEC / NBLK_STATS / 8);
    #pragma unroll 1
    for (int it = 0; it < NVEC / NBLK_STATS / 8; ++it) {
        int v  = base + it;
        int bi = indI[v];                              // wave-uniform
        float xv = x[(size_t)v * DIM + lane];          // 256B coalesced
        atomicAdd(&acc[bi][lane], xv);                 // ds_add_f32
        if (lane == 0) atomicAdd(&pcnt[bi], 1.0f);     // exact int sums
    }
    __syncthreads();

    // flush: skip zeros (codes absent from this block)
    #pragma unroll 1
    for (int i = tid; i < K * DIM; i += 512) {
        float s = ((float*)acc)[i];
        if (s != 0.0f) atomicAdd(&pesum[i], s);
    }
}

// ============ finalize (merged): 64 blocks, one per d ====================
// Each block recomputes ncs[j] and n with the proven op sequence (cj is
// the single atomic count — exact integer; same shuffle tree) -> n
// bit-identical in every block. Block 0 additionally writes ncs, diff.
__global__ __launch_bounds__(512) void vq_finalize(
    const float* __restrict__ cluster_size,
    const float* __restrict__ embed_avg,
    const float* __restrict__ ws,
    float* __restrict__ out)
{
    __shared__ float wsum[8];
    __shared__ float dsum_sh[8];
    __shared__ float n_sh;
    int d = blockIdx.x;     // 0..63
    int j = threadIdx.x;    // 0..511

    float cj = ws[PCNT_OFF + j];        // exact integer (atomic 1.0f sums)
    float ncs = DECAYF * cluster_size[j] + OMDF * cj;
    if (d == 0) out[NCS_OFF + j] = ncs;

    // diff partial sum only needed in block 0 (d uniform per block)
    float dsum = 0.0f;
    if (d == 0) {
        #pragma unroll
        for (int k = 0; k < NBLK_ASSIGN / 512; ++k)
            dsum += ws[DPART_OFF + k * 512 + j];
    }

    float s = ncs;
    #pragma unroll
    for (int off = 32; off > 0; off >>= 1) {
        s    += __shfl_down(s, off);
        dsum += __shfl_down(dsum, off);
    }
    if ((j & 63) == 0) { wsum[j >> 6] = s; dsum_sh[j >> 6] = dsum; }
    __syncthreads();
    if (j == 0) {
        float n = 0.f, dtot = 0.f;
        #pragma unroll
        for (int w = 0; w < 8; ++w) { n += wsum[w]; dtot += dsum_sh[w]; }
        n_sh = n;
        if (d == 0) out[DIFF_OFF] = dtot * (1.0f / 8388608.0f);  // 2^23: exact
    }
    __syncthreads();
    float n   = n_sh;
    float csz = (ncs + EPSF) / (n + (float)K * EPSF) * n;

    float es = ws[PESUM_OFF + (size_t)j * DIM + d];   // atomic-accumulated
    float ea = DECAYF * embed_avg[d * K + j] + OMDF * es;
    out[NEA_OFF + d * K + j] = ea;        // coalesced over j
    out[NE_OFF  + d * K + j] = ea / csz;
}

// ============ launch ============
extern "C" void kernel_launch(void* const* d_in, const int* in_sizes, int n_in,
                              void* d_out, int out_size, void* d_ws, size_t ws_size,
                              hipStream_t stream) {
    const float* x            = (const float*)d_in[0];
    const float* embed        = (const float*)d_in[1];
    const float* cluster_size = (const float*)d_in[2];
    const float* embed_avg    = (const float*)d_in[3];
    float* out = (float*)d_out;
    float* ws  = (float*)d_ws;
    int*   indI = (int*)(ws + INDI_OFF);

    vq_prep<<<2 + STATZ_N / 256, 256, 0, stream>>>(embed, ws);
    vq_assign<<<NBLK_ASSIGN, 256, 0, stream>>>(
        x, ws + ET_OFF, ws + C_OFF, indI, ws + DPART_OFF, out);
    vq_stats<<<NBLK_STATS, 512, 0, stream>>>(
        x, indI, ws + PCNT_OFF, ws + PESUM_OFF);
    vq_finalize<<<DIM, K, 0, stream>>>(cluster_size, embed_avg, ws, out);
}

// Round 14
// 262.090 us; speedup vs baseline: 2.1737x; 2.1737x over previous
//
#include <hip/hip_runtime.h>

// ---------------- problem constants ----------------
#define NVEC  131072      // 32*4096 vectors
#define DIM   64
#define K     512
#define DECAYF 0.99f
#define OMDF   0.01f
#define EPSF   1e-5f
#define VPB   128                 // vectors per block: 64 lanes x 2 vectors
#define NBLK_ASSIGN (NVEC / VPB)  // 1024 blocks, 4 waves each

// ---------------- output layout (floats, concatenated in return order) ----
#define Q_OFF    0
#define DIFF_OFF 8388608
#define IND_OFF  8388609
#define NE_OFF   8519681
#define NCS_OFF  8552449
#define NEA_OFF  8552961

// ---------------- ws layout (floats) — ~1.2 MB ----
#define ET_OFF    0        // E^T : K x DIM
#define C_OFF     32768    // np-order sum(E*E, axis=0) : K
#define DPART_OFF 33280    // per-assign-block diff partials : 1024
#define INDI_OFF  35328    // int copy of indices : NVEC
#define PCNT_OFF  166400   // count partials : 4 x K
#define PESUM_OFF 168448   // esum partials : 4 x K x DIM
#define NSH_OFF   299520   // scalar n (1 float) for split finalize
// end: 299521 floats = 1.17 MB (known-safe: r4 used 1.33 MB)

// ============ prep: transpose embed -> E^T, C_j = np.sum(E*E, axis=0) ====
__global__ __launch_bounds__(256) void vq_prep(const float* __restrict__ embed,
                                               float* __restrict__ ws) {
    #pragma clang fp contract(off)
    int j = blockIdx.x * 256 + threadIdx.x;
    float c = 0.0f;
    for (int d = 0; d < DIM; ++d) {
        float v = embed[d * K + j];           // coalesced across j
        ws[ET_OFF + j * DIM + d] = v;
        float t = v * v;
        c = c + t;
    }
    ws[C_OFF + j] = c;
}

// ============ main: np-fp32-replica argmin — R9-exact (best: 263.5 total) =
// Design-space verdicts after 14 measurements (all on-HW):
//   - e-delivery pipes: SMEM stream is the optimum (this form, 163-168 µs
//     across 5 configs). VMEM dead (R2 592 / R10 973 µs). LDS broadcast
//     dead (R3 254 µs). SMEM+R=1 inflates VALU 2.4x (R1).
//   - occupancy: wpe(3) best; wpe(4+) spills catastrophically (R5), no
//     attr splits to AGPRs (R6), wpe(2) loses TLP (R4).
//   - stats fusion/restructure: fused atomics +104 µs (R12: 256
//     adds/address L2 serialization); LDS-accum +170 µs (R13: 32 blocks =
//     12.5% of chip + serial dep chain); 4-code grouping neutral (R11).
__global__ __launch_bounds__(256)
__attribute__((amdgpu_waves_per_eu(3)))
void vq_assign(
    const float* __restrict__ x,
    const float* __restrict__ ET,      // ws + ET_OFF
    const float* __restrict__ C,       // ws + C_OFF
    int*   __restrict__ indI,          // ws + INDI_OFF
    float* __restrict__ dpart,         // ws + DPART_OFF
    float* __restrict__ out)
{
    #pragma clang fp contract(off)
    __shared__ float sda[4][64], sdb[4][64];
    __shared__ int   sia[4][64], sib[4][64];
    __shared__ int   sba[64], sbb[64];
    __shared__ float wdl[4];

    int lane = threadIdx.x & 63;
    int wq   = __builtin_amdgcn_readfirstlane(threadIdx.x >> 6); // 0..3
    int va   = blockIdx.x * VPB + lane;
    int vb   = va + 64;
    const float* fxa = x + (size_t)va * DIM;
    const float* fxb = x + (size_t)vb * DIM;

    float fa[DIM], fb[DIM];
    #pragma unroll
    for (int k = 0; k < DIM / 4; ++k) {
        float4 t = ((const float4*)fxa)[k];
        fa[4*k+0] = t.x; fa[4*k+1] = t.y; fa[4*k+2] = t.z; fa[4*k+3] = t.w;
    }
    #pragma unroll
    for (int k = 0; k < DIM / 4; ++k) {
        float4 t = ((const float4*)fxb)[k];
        fb[4*k+0] = t.x; fb[4*k+1] = t.y; fb[4*k+2] = t.z; fb[4*k+3] = t.w;
    }

    // Pin fa/fb in VGPRs (identity asm: values defined by asm can't be
    // rematerialized from memory).
    #define PIN16(a, b) asm volatile("" \
        : "+v"(a[(b)+0]),  "+v"(a[(b)+1]),  "+v"(a[(b)+2]),  "+v"(a[(b)+3]), \
          "+v"(a[(b)+4]),  "+v"(a[(b)+5]),  "+v"(a[(b)+6]),  "+v"(a[(b)+7]), \
          "+v"(a[(b)+8]),  "+v"(a[(b)+9]),  "+v"(a[(b)+10]), "+v"(a[(b)+11]), \
          "+v"(a[(b)+12]), "+v"(a[(b)+13]), "+v"(a[(b)+14]), "+v"(a[(b)+15]))
    PIN16(fa, 0); PIN16(fa, 16); PIN16(fa, 32); PIN16(fa, 48);
    PIN16(fb, 0); PIN16(fb, 16); PIN16(fb, 32); PIN16(fb, 48);
    #undef PIN16

    // A per vector: numpy pairwise, n=64 -> 8 accumulators stride 8, then
    // ((r0+r1)+(r2+r3))+((r4+r5)+(r6+r7)). Plain mul+add (contract off).
    float ra[8], rb[8];
    #pragma unroll
    for (int k = 0; k < 8; ++k) { ra[k] = fa[k] * fa[k]; rb[k] = fb[k] * fb[k]; }
    #pragma unroll
    for (int b = 1; b < 8; ++b) {
        #pragma unroll
        for (int k = 0; k < 8; ++k) {
            float t0 = fa[8*b + k] * fa[8*b + k];
            ra[k] = ra[k] + t0;
            float t1 = fb[8*b + k] * fb[8*b + k];
            rb[k] = rb[k] + t1;
        }
    }
    float Aa = ((ra[0] + ra[1]) + (ra[2] + ra[3])) + ((ra[4] + ra[5]) + (ra[6] + ra[7]));
    float Ab = ((rb[0] + rb[1]) + (rb[2] + rb[3])) + ((rb[4] + rb[5]) + (rb[6] + rb[7]));

    // wave-uniform code segment -> s_load e-stream; one scalar feeds 2 FMAs.
    // unroll 1: one j-row of staging in flight.
    const float* eseg = ET + (size_t)wq * 128 * DIM;
    const float* Cseg = C + wq * 128;
    float bda = 3.0e38f, bdb = 3.0e38f;
    int   bia = wq * 128, bib = wq * 128;
    #pragma unroll 1
    for (int jj = 0; jj < 128; ++jj) {
        const float* e = eseg + jj * DIM;
        float ma = 0.0f, mb = 0.0f;
        #pragma unroll
        for (int d = 0; d < DIM; ++d) {
            float ev = e[d];
            ma = __builtin_fmaf(fa[d], ev, ma);
            mb = __builtin_fmaf(fb[d], ev, mb);
        }
        int j = wq * 128 + jj;
        float Cv = Cseg[jj];
        float t1a = 2.0f * ma;           // exact (x2)
        float t2a = Aa - t1a;            // rounded
        float da  = t2a + Cv;            // rounded
        float t1b = 2.0f * mb;
        float t2b = Ab - t1b;
        float db  = t2b + Cv;
        if (da < bda) { bda = da; bia = j; }
        if (db < bdb) { bdb = db; bib = j; }
    }

    sda[wq][lane] = bda; sia[wq][lane] = bia;
    sdb[wq][lane] = bdb; sib[wq][lane] = bib;
    __syncthreads();

    if (wq == 0) {
        // 4-way merge, ascending q, tie -> smaller index: numpy first-min.
        float bd = sda[0][lane]; int bi = sia[0][lane];
        #pragma unroll
        for (int q = 1; q < 4; ++q) {
            float d2 = sda[q][lane]; int i2 = sia[q][lane];
            if (d2 < bd || (d2 == bd && i2 < bi)) { bd = d2; bi = i2; }
        }
        sba[lane] = bi;
        out[IND_OFF + va] = (float)bi;   // coalesced
        indI[va] = bi;

        bd = sdb[0][lane]; bi = sib[0][lane];
        #pragma unroll
        for (int q = 1; q < 4; ++q) {
            float d2 = sdb[q][lane]; int i2 = sib[q][lane];
            if (d2 < bd || (d2 == bd && i2 < bi)) { bd = d2; bi = i2; }
        }
        sbb[lane] = bi;
        out[IND_OFF + vb] = (float)bi;
        indI[vb] = bi;
    }
    __syncthreads();

    // epilogue: wave0 -> va rows (vs pinned fa), wave1 -> vb rows (vs fb);
    // waves 2,3 idle (wdl = 0, dpart grouping stays wdl[0]+wdl[1]).
    float dl = 0.0f;
    if (wq == 0) {
        int bsel = sba[lane];
        const float4* qr = (const float4*)(ET + (size_t)bsel * DIM);
        float4* orow = (float4*)(out + Q_OFF + (size_t)va * DIM);
        #pragma unroll
        for (int k = 0; k < 16; ++k) {
            float4 tq = qr[k];
            float r0 = tq.x - fa[4*k+0];
            float r1 = tq.y - fa[4*k+1];
            float r2 = tq.z - fa[4*k+2];
            float r3 = tq.w - fa[4*k+3];
            dl = __builtin_fmaf(r0, r0, dl); dl = __builtin_fmaf(r1, r1, dl);
            dl = __builtin_fmaf(r2, r2, dl); dl = __builtin_fmaf(r3, r3, dl);
            orow[k] = tq;
        }
    } else if (wq == 1) {
        int bsel = sbb[lane];
        const float4* qr = (const float4*)(ET + (size_t)bsel * DIM);
        float4* orow = (float4*)(out + Q_OFF + (size_t)vb * DIM);
        #pragma unroll
        for (int k = 0; k < 16; ++k) {
            float4 tq = qr[k];
            float r0 = tq.x - fb[4*k+0];
            float r1 = tq.y - fb[4*k+1];
            float r2 = tq.z - fb[4*k+2];
            float r3 = tq.w - fb[4*k+3];
            dl = __builtin_fmaf(r0, r0, dl); dl = __builtin_fmaf(r1, r1, dl);
            dl = __builtin_fmaf(r2, r2, dl); dl = __builtin_fmaf(r3, r3, dl);
            orow[k] = tq;
        }
    }

    #pragma unroll
    for (int off = 32; off > 0; off >>= 1) dl += __shfl_down(dl, off);
    if (lane == 0) wdl[wq] = dl;
    __syncthreads();
    if (threadIdx.x == 0)
        dpart[blockIdx.x] = ((wdl[0] + wdl[1]) + (wdl[2] + wdl[3]));
}

// ============ stats: 4 blocks x 8 waves per code, int4 ballot scan =======
__global__ __launch_bounds__(512) void vq_stats(
    const float* __restrict__ x,
    const int* __restrict__ indI,      // ws + INDI_OFF
    float* __restrict__ pcnt,          // ws + PCNT_OFF   [4][K]
    float* __restrict__ pesum)         // ws + PESUM_OFF  [4][K][DIM]
{
    __shared__ float p[8][DIM];
    __shared__ float c[8];
    int j    = blockIdx.x >> 2;
    int q    = blockIdx.x & 3;
    int lane = threadIdx.x & 63;
    int w    = __builtin_amdgcn_readfirstlane(threadIdx.x >> 6);

    int seg  = q * 8 + w;              // 0..31
    int base = seg * (NVEC / 32);      // 4096 ids per segment

    float acc = 0.0f;
    int   cnt = 0;
    for (int i = 0; i < NVEC / 32; i += 256) {
        int4 idv = ((const int4*)(indI + base + i))[lane];  // 256 ids/wave
        unsigned long long m0 = __ballot(idv.x == j);
        unsigned long long m1 = __ballot(idv.y == j);
        unsigned long long m2 = __ballot(idv.z == j);
        unsigned long long m3 = __ballot(idv.w == j);
        cnt += (int)(__popcll(m0) + __popcll(m1) + __popcll(m2) + __popcll(m3));
        while (m0) { int b = __builtin_ctzll(m0); m0 &= m0 - 1;
                     acc += x[(size_t)(base + i + 4*b + 0) * DIM + lane]; }
        while (m1) { int b = __builtin_ctzll(m1); m1 &= m1 - 1;
                     acc += x[(size_t)(base + i + 4*b + 1) * DIM + lane]; }
        while (m2) { int b = __builtin_ctzll(m2); m2 &= m2 - 1;
                     acc += x[(size_t)(base + i + 4*b + 2) * DIM + lane]; }
        while (m3) { int b = __builtin_ctzll(m3); m3 &= m3 - 1;
                     acc += x[(size_t)(base + i + 4*b + 3) * DIM + lane]; }
    }
    p[w][lane] = acc;
    if (lane == 0) c[w] = (float)cnt;
    __syncthreads();
    if (w == 0) {
        float s = ((p[0][lane] + p[1][lane]) + (p[2][lane] + p[3][lane]))
                + ((p[4][lane] + p[5][lane]) + (p[6][lane] + p[7][lane]));
        pesum[((size_t)q * K + j) * DIM + lane] = s;
        if (lane == 0)
            pcnt[q * K + j] = ((c[0] + c[1]) + (c[2] + c[3]))
                            + ((c[4] + c[5]) + (c[6] + c[7]));
    }
}

// ============ finalize stage 1: scalars (ncs, n, diff) — 1 block =========
__global__ __launch_bounds__(512) void vq_finalize1(
    const float* __restrict__ cluster_size,
    float* __restrict__ ws,
    float* __restrict__ out)
{
    __shared__ float wsum[8];
    __shared__ float dsum_sh[8];
    int j = threadIdx.x;  // 512 threads, one per code

    float cj = ((ws[PCNT_OFF + 0*K + j] + ws[PCNT_OFF + 1*K + j])
              + (ws[PCNT_OFF + 2*K + j] + ws[PCNT_OFF + 3*K + j]));
    float ncs = DECAYF * cluster_size[j] + OMDF * cj;
    out[NCS_OFF + j] = ncs;

    // diff: sum 1024 block partials (deterministic)
    float dsum = 0.0f;
    #pragma unroll
    for (int k = 0; k < NBLK_ASSIGN / 512; ++k)
        dsum += ws[DPART_OFF + k * 512 + j];

    float s = ncs;
    #pragma unroll
    for (int off = 32; off > 0; off >>= 1) {
        s    += __shfl_down(s, off);
        dsum += __shfl_down(dsum, off);
    }
    if ((j & 63) == 0) { wsum[j >> 6] = s; dsum_sh[j >> 6] = dsum; }
    __syncthreads();
    if (j == 0) {
        float n = 0.f, dtot = 0.f;
        #pragma unroll
        for (int w = 0; w < 8; ++w) { n += wsum[w]; dtot += dsum_sh[w]; }
        ws[NSH_OFF] = n;
        out[DIFF_OFF] = dtot * (1.0f / 8388608.0f);  // 2^23: exact
    }
}

// ============ finalize stage 2: embed EMA + normalize — 64 blocks ========
__global__ __launch_bounds__(512) void vq_finalize2(
    const float* __restrict__ embed_avg,
    const float* __restrict__ ws,
    float* __restrict__ out)
{
    int d = blockIdx.x;     // 0..63
    int j = threadIdx.x;    // 0..511

    float ncs = out[NCS_OFF + j];
    float n   = ws[NSH_OFF];
    float csz = (ncs + EPSF) / (n + (float)K * EPSF) * n;

    float es = ((ws[PESUM_OFF + ((size_t)0*K + j) * DIM + d]
               + ws[PESUM_OFF + ((size_t)1*K + j) * DIM + d])
              + (ws[PESUM_OFF + ((size_t)2*K + j) * DIM + d]
               + ws[PESUM_OFF + ((size_t)3*K + j) * DIM + d]));
    float ea = DECAYF * embed_avg[d * K + j] + OMDF * es;
    out[NEA_OFF + d * K + j] = ea;        // coalesced over j
    out[NE_OFF  + d * K + j] = ea / csz;
}

// ============ launch ============
extern "C" void kernel_launch(void* const* d_in, const int* in_sizes, int n_in,
                              void* d_out, int out_size, void* d_ws, size_t ws_size,
                              hipStream_t stream) {
    const float* x            = (const float*)d_in[0];
    const float* embed        = (const float*)d_in[1];
    const float* cluster_size = (const float*)d_in[2];
    const float* embed_avg    = (const float*)d_in[3];
    float* out = (float*)d_out;
    float* ws  = (float*)d_ws;
    int*   indI = (int*)(ws + INDI_OFF);

    vq_prep<<<K / 256, 256, 0, stream>>>(embed, ws);
    vq_assign<<<NBLK_ASSIGN, 256, 0, stream>>>(
        x, ws + ET_OFF, ws + C_OFF, indI, ws + DPART_OFF, out);
    vq_stats<<<K * 4, 512, 0, stream>>>(
        x, indI, ws + PCNT_OFF, ws + PESUM_OFF);
    vq_finalize1<<<1, K, 0, stream>>>(cluster_size, ws, out);
    vq_finalize2<<<DIM, K, 0, stream>>>(embed_avg, ws, out);
}